// Round 2
// baseline (78.175 us; speedup 1.0000x reference)
//
#include <hip/hip_runtime.h>

// Additive (Bahdanau) attention, f32.
// b=4, q=256, k=1024, emb=256, h=128, v=256.
// out  = (4,256,256)  at d_out offset 0
// attn = (4,256,1024) at d_out offset 262144
//
// tanh(Hq+Hk) = 1 - 2/(e^{2Hq}*e^{2Hk} + 1).  Projections store
// Eq = exp2(2*log2e*Hq), Ek = exp2(2*log2e*Hk).  Scores fold FOUR h-terms
// into ONE rcp:  w0/A+w1/B+w2/C+w3/D = (n01*CD + n23*AB) * rcp(AB*CD).
// Softmax is shift-invariant, so the constant Wsum term is dropped and
// z' = -2 * sum_h w[h]*rcp(Eq*Ek+1) feeds softmax directly.
// Kernels: A (proj) | BC (score+softmax fused) | D1 (split-k PV) | D2 (reduce).

#define L2E 1.4426950408889634f

// ---------------------------------------------------------------------------
// Kernel A: projections + exp epilogue.  Eq = exp2(2L2E*(query@wq)), same Ek.
// Blocks 0..63 -> Eq (1024 rows), 64..319 -> Ek (4096 rows).
// W staged through LDS in 64-row e-chunks (32 KB): each block reads the
// 128 KB weight matrix from global exactly once.
// ---------------------------------------------------------------------------
__global__ __launch_bounds__(256) void aa_proj_kernel(
    const float* __restrict__ query, const float* __restrict__ key,
    const float* __restrict__ wq, const float* __restrict__ wk,
    float* __restrict__ Eq, float* __restrict__ Ek)
{
    __shared__ float rows_s[16 * 256];   // 16 KB
    __shared__ float w_s[64 * 128];      // 32 KB
    const int i = blockIdx.x;
    const int t = threadIdx.x;

    const float* src;
    const float* W;
    float* dst;
    if (i < 64) {
        const int r0 = i * 16;
        src = query + r0 * 256; W = wq; dst = Eq + r0 * 128;
    } else {
        const int r0 = (i - 64) * 16;
        src = key + r0 * 256; W = wk; dst = Ek + r0 * 128;
    }

#pragma unroll
    for (int j = 0; j < 4; ++j) {
        const int f = t * 4 + j * 1024;
        *(float4*)&rows_s[f] = *(const float4*)&src[f];
    }

    const int rgr = t >> 5;
    const int hg = t & 31;
    const int ri0 = rgr * 2;
    const int h0 = hg * 4;

    float acc0[4] = {0.f, 0.f, 0.f, 0.f};
    float acc1[4] = {0.f, 0.f, 0.f, 0.f};

    for (int ec = 0; ec < 256; ec += 64) {
        __syncthreads();   // first iter: covers rows_s; later: w_s readers done
#pragma unroll
        for (int j = 0; j < 8; ++j) {
            const int f = t * 4 + j * 1024;
            *(float4*)&w_s[f] = *(const float4*)&W[ec * 128 + f];
        }
        __syncthreads();

        for (int e = 0; e < 64; e += 4) {
            float a0[4], a1[4];
            *(float4*)a0 = *(const float4*)&rows_s[ri0 * 256 + ec + e];
            *(float4*)a1 = *(const float4*)&rows_s[(ri0 + 1) * 256 + ec + e];
#pragma unroll
            for (int j = 0; j < 4; ++j) {
                float w[4];
                *(float4*)w = *(const float4*)&w_s[(e + j) * 128 + h0];
#pragma unroll
                for (int c = 0; c < 4; ++c) {
                    acc0[c] = fmaf(a0[j], w[c], acc0[c]);
                    acc1[c] = fmaf(a1[j], w[c], acc1[c]);
                }
            }
        }
    }

    float o0[4], o1[4];
#pragma unroll
    for (int c = 0; c < 4; ++c) {
        o0[c] = __builtin_amdgcn_exp2f(acc0[c] * (2.0f * L2E));
        o1[c] = __builtin_amdgcn_exp2f(acc1[c] * (2.0f * L2E));
    }
    *(float4*)&dst[ri0 * 128 + h0] = *(float4*)o0;
    *(float4*)&dst[(ri0 + 1) * 128 + h0] = *(float4*)o1;
}

// ---------------------------------------------------------------------------
// Kernel BC: fused score + softmax.  256 blocks x 512 thr (8 waves).
// Block = 4 q-rows x full k=1024 for one batch; bid = b*64 + qt.
// Thread (qp = t>>7 wave-uniform, kc = t&127) owns score z'[c] for
// (row qp, k = c*128+kc), c = 0..7 Ek-chunks of 128 rows staged in LDS
// ([128][132] pad -> conflict-free b128 reads) with reg-prefetch overlap.
// Eq row + wv are read as wave-uniform global loads (L1 broadcast) - no LDS.
// Softmax: per-row max/sum via shfl + 2-wave LDS exchange; writes a only.
// ---------------------------------------------------------------------------
__global__ __launch_bounds__(512) void aa_score_softmax_kernel(
    const float* __restrict__ Eq, const float* __restrict__ Ek,
    const float* __restrict__ wv, float* __restrict__ a)
{
    __shared__ float ek_s[128 * 132];   // 67584 B

    const int bid = blockIdx.x;
    const int b  = bid >> 6;
    const int qt = bid & 63;
    const int t  = threadIdx.x;
    const int qp = t >> 7;     // 0..3, constant within a wave
    const int kc = t & 127;
    const int q0g = b * 256 + qt * 4;

    // wave-uniform Eq row pointer (readfirstlane -> SGPR base -> s_load)
    const int qrow = __builtin_amdgcn_readfirstlane(q0g + qp);
    const float* eqp = Eq + (size_t)qrow * 128;
    const float* ekb = Ek + (size_t)b * 131072;   // batch base (1024*128)

    float pf[8][4];
    // prefetch chunk 0
#pragma unroll
    for (int j = 0; j < 8; ++j) {
        const int g = t * 4 + j * 2048;
        *(float4*)pf[j] = *(const float4*)&ekb[g];
    }

    float zv[8];

#pragma unroll
    for (int c = 0; c < 8; ++c) {
        // commit prefetched chunk c to LDS ([row][col] with 132 pad)
#pragma unroll
        for (int j = 0; j < 8; ++j) {
            const int g = t * 4 + j * 2048;
            const int row = g >> 7;
            const int col = g & 127;
            *(float4*)&ek_s[row * 132 + col] = *(float4*)pf[j];
        }
        __syncthreads();

        // issue prefetch of chunk c+1 (latency hides under compute)
        if (c < 7) {
            const float* nx = ekb + (size_t)(c + 1) * 16384;
#pragma unroll
            for (int j = 0; j < 8; ++j) {
                const int g = t * 4 + j * 2048;
                *(float4*)pf[j] = *(const float4*)&nx[g];
            }
        }

        // score for (row qp, k = c*128 + kc): quad-rcp fold over h
        float acc = 0.f;
        const float* ekr = ek_s + kc * 132;
#pragma unroll 8
        for (int h = 0; h < 128; h += 4) {
            float x[4], w4[4], y[4];
            *(float4*)x  = *(const float4*)(eqp + h);   // uniform
            *(float4*)w4 = *(const float4*)(wv + h);    // uniform
            *(float4*)y  = *(const float4*)(ekr + h);
            const float A = fmaf(x[0], y[0], 1.0f);
            const float B = fmaf(x[1], y[1], 1.0f);
            const float C = fmaf(x[2], y[2], 1.0f);
            const float D = fmaf(x[3], y[3], 1.0f);
            const float AB = A * B;
            const float CD = C * D;
            const float n01 = fmaf(w4[1], A, w4[0] * B);
            const float n23 = fmaf(w4[3], C, w4[2] * D);
            const float num = fmaf(n01, CD, n23 * AB);
            acc = fmaf(num, __builtin_amdgcn_rcpf(AB * CD), acc);
        }
        zv[c] = -2.0f * acc;
        __syncthreads();
    }

    // ---- softmax over k=1024 for row qp (held by waves 2qp, 2qp+1) ----
    float m = zv[0];
#pragma unroll
    for (int c = 1; c < 8; ++c) m = fmaxf(m, zv[c]);
#pragma unroll
    for (int off = 32; off; off >>= 1) m = fmaxf(m, __shfl_xor(m, off));

    float* red = ek_s;              // ek_s dead after last compute barrier
    const int w = t >> 6;           // wave id 0..7
    if ((t & 63) == 0) red[w] = m;
    __syncthreads();
    m = fmaxf(red[qp * 2], red[qp * 2 + 1]);

    float e[8];
    float s = 0.f;
#pragma unroll
    for (int c = 0; c < 8; ++c) {
        e[c] = __builtin_amdgcn_exp2f((zv[c] - m) * L2E);
        s += e[c];
    }
#pragma unroll
    for (int off = 32; off; off >>= 1) s += __shfl_xor(s, off);
    if ((t & 63) == 0) red[8 + w] = s;
    __syncthreads();
    s = red[8 + qp * 2] + red[8 + qp * 2 + 1];

    const float inv = __builtin_amdgcn_rcpf(s);
    float* ar = a + (size_t)(q0g + qp) * 1024 + kc;
#pragma unroll
    for (int c = 0; c < 8; ++c) ar[c * 128] = e[c] * inv;
}

// ---------------------------------------------------------------------------
// Kernel D1: split-k PV partial (16-q tile).
// Grid: 4b x 16qt x 8kt = 512 blocks, 256 thr = 4 waves.
// Block tile: 16q x 256v over a 128-k chunk; wave w takes k-sub [w*32,+32).
// part layout: [bid][16 q][256 v], bid = ((b*16+qt)*8+kt).
// ---------------------------------------------------------------------------
__global__ __launch_bounds__(256) void aa_pv_partial_kernel(
    const float* __restrict__ a, const float* __restrict__ value,
    float* __restrict__ part)
{
    __shared__ float a_s[16][128];      // 8 KB
    __shared__ float red_s[4][4096];    // 64 KB
    const int bid = blockIdx.x;
    const int b  = bid >> 7;
    const int qt = (bid >> 3) & 15;
    const int kt = bid & 7;
    const int t = threadIdx.x;

#pragma unroll
    for (int j = 0; j < 2; ++j) {
        const int f = t * 4 + j * 1024;
        const int qs = f >> 7;
        const int k0 = f & 127;
        const float* arow = a + (size_t)(b * 256 + qt * 16 + qs) * 1024 + kt * 128;
        *(float4*)&a_s[qs][k0] = *(const float4*)&arow[k0];
    }
    __syncthreads();

    const int w = t >> 6;       // wave id, k-sub = w*32
    const int lane = t & 63;
    const int v0 = lane * 4;    // 64 lanes x 4 = 256 v
    const float* vp = value + (size_t)b * 262144
                    + (size_t)(kt * 128 + w * 32) * 256 + v0;

    float acc[16][4] = {};

#pragma unroll 2
    for (int k4 = 0; k4 < 8; ++k4) {          // 8 groups of 4 k
        float vv[4][4];
#pragma unroll
        for (int r = 0; r < 4; ++r)
            *(float4*)vv[r] = *(const float4*)(vp + (size_t)(k4 * 4 + r) * 256);
#pragma unroll
        for (int q = 0; q < 16; ++q) {
            float aq[4];
            *(float4*)aq = *(const float4*)&a_s[q][w * 32 + k4 * 4];
#pragma unroll
            for (int r = 0; r < 4; ++r)
#pragma unroll
                for (int c = 0; c < 4; ++c)
                    acc[q][c] = fmaf(aq[r], vv[r][c], acc[q][c]);
        }
    }

    float* rs = &red_s[w][v0];
#pragma unroll
    for (int q = 0; q < 16; ++q)
        *(float4*)(rs + q * 256) = *(float4*)acc[q];
    __syncthreads();

    const int g = t >> 6;
    const int l4 = (t & 63) * 4;
    float* po = part + (size_t)bid * 4096;
#pragma unroll
    for (int c = 0; c < 4; ++c) {
        const int i = g * 1024 + c * 256 + l4;
        float s[4];
        *(float4*)s = *(const float4*)&red_s[0][i];
#pragma unroll
        for (int ww = 1; ww < 4; ++ww) {
            float x[4];
            *(float4*)x = *(const float4*)&red_s[ww][i];
            s[0] += x[0]; s[1] += x[1]; s[2] += x[2]; s[3] += x[3];
        }
        *(float4*)(po + i) = *(float4*)s;
    }
}

// ---------------------------------------------------------------------------
// Kernel D2: fixed-order 8-way reduce of partials -> out.
// part layout: [(b*16+qt)*8+kt][16 q][256 v].
// ---------------------------------------------------------------------------
__global__ __launch_bounds__(256) void aa_pv_reduce_kernel(
    const float* __restrict__ part, float* __restrict__ out)
{
    const int idx = blockIdx.x * 256 + threadIdx.x;
    const int o = idx * 4;
    const int row = o >> 8;
    const int v = o & 255;
    const int b = row >> 8;
    const int q = row & 255;
    const int qt = q >> 4;
    const int qr = q & 15;
    const float* p = part + (size_t)((b * 16 + qt) * 8) * 4096 + qr * 256 + v;

    float s[4] = {0.f, 0.f, 0.f, 0.f};
#pragma unroll
    for (int kt = 0; kt < 8; ++kt) {
        float x[4];
        *(float4*)x = *(const float4*)(p + (size_t)kt * 4096);
        s[0] += x[0]; s[1] += x[1]; s[2] += x[2]; s[3] += x[3];
    }
    *(float4*)&out[o] = *(float4*)s;
}

// ---------------------------------------------------------------------------
extern "C" void kernel_launch(void* const* d_in, const int* in_sizes, int n_in,
                              void* d_out, int out_size, void* d_ws, size_t ws_size,
                              hipStream_t stream)
{
    const float* query = (const float*)d_in[0];  // (4,256,256)
    const float* key   = (const float*)d_in[1];  // (4,1024,256)
    const float* value = (const float*)d_in[2];  // (4,1024,256)
    const float* wq    = (const float*)d_in[3];  // (256,128)
    const float* wk    = (const float*)d_in[4];  // (256,128)
    const float* wv    = (const float*)d_in[5];  // (128,)

    float* out   = (float*)d_out;                // (4,256,256)
    float* a_out = out + 4 * 256 * 256;          // (4,256,1024)

    float* ws = (float*)d_ws;
    float* Eq   = ws;                            // 131072 f32
    float* Ek   = ws + 131072;                   // 524288 f32
    float* part = ws + 131072 + 524288;          // 2097152 f32 (8 MB)

    aa_proj_kernel<<<320, 256, 0, stream>>>(query, key, wq, wk, Eq, Ek);
    aa_score_softmax_kernel<<<256, 512, 0, stream>>>(Eq, Ek, wv, a_out);
    aa_pv_partial_kernel<<<512, 256, 0, stream>>>(a_out, value, part);
    aa_pv_reduce_kernel<<<256, 256, 0, stream>>>(part, out);
}

// Round 3
// 49.165 us; speedup vs baseline: 1.5901x; 1.5901x over previous
//
#include <hip/hip_runtime.h>

// Additive (Bahdanau) attention, f32.
// b=4, q=256, k=1024, emb=256, h=128, v=256.
// out  = (4,256,256)  at d_out offset 0
// attn = (4,256,1024) at d_out offset 262144
//
// tanh(Hq+Hk) = 1 - 2/(e^{2Hq}*e^{2Hk} + 1).  Projections store
// Eq = exp2(2*log2e*Hq), Ek = exp2(2*log2e*Hk).  Scores fold FOUR h-terms
// into ONE rcp:  w0/A+w1/B+w2/C+w3/D = (n01*CD + n23*AB) * rcp(AB*CD).
// Softmax is shift-invariant -> the constant Wsum term is dropped:
// z' = -2 * sum_h w[h]*rcp(Eq*Ek+1).
// Kernels: A (proj) | B (scores) | C (softmax) | D1 (split-4 PV) | D2 (reduce).

#define L2E 1.4426950408889634f

// ---------------------------------------------------------------------------
// Kernel A: projections + exp epilogue.  Eq = exp2(2L2E*(query@wq)), same Ek.
// Blocks 0..63 -> Eq (1024 rows), 64..319 -> Ek (4096 rows).
// W staged through LDS in 64-row e-chunks (32 KB): each block reads the
// 128 KB weight matrix from global exactly once.
// ---------------------------------------------------------------------------
__global__ __launch_bounds__(256) void aa_proj_kernel(
    const float* __restrict__ query, const float* __restrict__ key,
    const float* __restrict__ wq, const float* __restrict__ wk,
    float* __restrict__ Eq, float* __restrict__ Ek)
{
    __shared__ float rows_s[16 * 256];   // 16 KB
    __shared__ float w_s[64 * 128];      // 32 KB
    const int i = blockIdx.x;
    const int t = threadIdx.x;

    const float* src;
    const float* W;
    float* dst;
    if (i < 64) {
        const int r0 = i * 16;
        src = query + r0 * 256; W = wq; dst = Eq + r0 * 128;
    } else {
        const int r0 = (i - 64) * 16;
        src = key + r0 * 256; W = wk; dst = Ek + r0 * 128;
    }

#pragma unroll
    for (int j = 0; j < 4; ++j) {
        const int f = t * 4 + j * 1024;
        *(float4*)&rows_s[f] = *(const float4*)&src[f];
    }

    const int rgr = t >> 5;
    const int hg = t & 31;
    const int ri0 = rgr * 2;
    const int h0 = hg * 4;

    float acc0[4] = {0.f, 0.f, 0.f, 0.f};
    float acc1[4] = {0.f, 0.f, 0.f, 0.f};

    for (int ec = 0; ec < 256; ec += 64) {
        __syncthreads();   // first iter: covers rows_s; later: w_s readers done
#pragma unroll
        for (int j = 0; j < 8; ++j) {
            const int f = t * 4 + j * 1024;
            *(float4*)&w_s[f] = *(const float4*)&W[ec * 128 + f];
        }
        __syncthreads();

        for (int e = 0; e < 64; e += 4) {
            float a0[4], a1[4];
            *(float4*)a0 = *(const float4*)&rows_s[ri0 * 256 + ec + e];
            *(float4*)a1 = *(const float4*)&rows_s[(ri0 + 1) * 256 + ec + e];
#pragma unroll
            for (int j = 0; j < 4; ++j) {
                float w[4];
                *(float4*)w = *(const float4*)&w_s[(e + j) * 128 + h0];
#pragma unroll
                for (int c = 0; c < 4; ++c) {
                    acc0[c] = fmaf(a0[j], w[c], acc0[c]);
                    acc1[c] = fmaf(a1[j], w[c], acc1[c]);
                }
            }
        }
    }

    float o0[4], o1[4];
#pragma unroll
    for (int c = 0; c < 4; ++c) {
        o0[c] = __builtin_amdgcn_exp2f(acc0[c] * (2.0f * L2E));
        o1[c] = __builtin_amdgcn_exp2f(acc1[c] * (2.0f * L2E));
    }
    *(float4*)&dst[ri0 * 128 + h0] = *(float4*)o0;
    *(float4*)&dst[(ri0 + 1) * 128 + h0] = *(float4*)o1;
}

// ---------------------------------------------------------------------------
// Kernel B: scores z' = -2*sum_h w[h]*rcp(fma(Eq,Ek,1)).
// Grid 512 = 4b x 16qt x 8kt; block tile 16q x 128k, 256 thr.
// Thread = 4q x 2k: qp = t>>6 (WAVE-UNIFORM -> eq + wv LDS reads are
// same-address broadcasts, ~free); kp = t&63 -> k cols {kp, kp+64}.
// Per h-group: 2 per-lane ek b128 reads + 5 broadcast reads, 8 quads.
// ---------------------------------------------------------------------------
__global__ __launch_bounds__(256) void aa_score_kernel(
    const float* __restrict__ Eq, const float* __restrict__ Ek,
    const float* __restrict__ wv, float* __restrict__ z)
{
    __shared__ float eq_s[16 * 128];     // 8 KB
    __shared__ float ek_s[128 * 132];    // 67.6 KB (pad -> even bank spread)
    __shared__ float wv_s[128];

    const int bid = blockIdx.x;
    const int b  = bid >> 7;
    const int qt = (bid >> 3) & 15;
    const int kt = bid & 7;
    const int q0g = b * 256 + qt * 16;
    const int k0g = b * 1024 + kt * 128;
    const int t = threadIdx.x;

    const float* eqsrc = Eq + (size_t)q0g * 128;
#pragma unroll
    for (int j = 0; j < 2; ++j) {
        const int f = t * 4 + j * 1024;
        *(float4*)&eq_s[f] = *(const float4*)&eqsrc[f];
    }
    const float* eksrc = Ek + (size_t)k0g * 128;
#pragma unroll
    for (int j = 0; j < 16; ++j) {
        const int f = t * 4 + j * 1024;
        const int ki = f >> 7;
        const int h = f & 127;
        *(float4*)&ek_s[ki * 132 + h] = *(const float4*)&eksrc[f];
    }
    if (t < 128) wv_s[t] = wv[t];
    __syncthreads();

    const int qp = t >> 6;     // 0..3, wave-uniform: rows qp*4 .. qp*4+3
    const int kp = t & 63;     // k cols kp, kp+64
    const float* eq0 = eq_s + (qp * 4) * 128;
    const float* eka = ek_s + kp * 132;
    const float* ekb = eka + 64 * 132;

    float acc[4][2] = {};

    // quad-rcp: sum_{j=0..3} w[j]/(x[j]*y[j]+1) with a single rcp.
    auto quad = [](const float* x, const float* y, const float* w, float& acc) {
        const float A = fmaf(x[0], y[0], 1.0f);
        const float B = fmaf(x[1], y[1], 1.0f);
        const float C = fmaf(x[2], y[2], 1.0f);
        const float D = fmaf(x[3], y[3], 1.0f);
        const float AB = A * B;
        const float CD = C * D;
        const float n01 = fmaf(w[1], A, w[0] * B);
        const float n23 = fmaf(w[3], C, w[2] * D);
        const float num = fmaf(n01, CD, n23 * AB);
        acc = fmaf(num, __builtin_amdgcn_rcpf(AB * CD), acc);
    };

#pragma unroll 4
    for (int h = 0; h < 128; h += 4) {
        float y0[4], y1[4], w4[4];
        *(float4*)y0 = *(const float4*)(eka + h);
        *(float4*)y1 = *(const float4*)(ekb + h);
        *(float4*)w4 = *(const float4*)(wv_s + h);
#pragma unroll
        for (int i = 0; i < 4; ++i) {
            float x[4];
            *(float4*)x = *(const float4*)(eq0 + i * 128 + h);   // broadcast
            quad(x, y0, w4, acc[i][0]);
            quad(x, y1, w4, acc[i][1]);
        }
    }

    const int kl = kt * 128 + kp;
#pragma unroll
    for (int i = 0; i < 4; ++i) {
        float* zr = z + (size_t)(q0g + qp * 4 + i) * 1024 + kl;
        zr[0]  = -2.0f * acc[i][0];
        zr[64] = -2.0f * acc[i][1];
    }
}

// ---------------------------------------------------------------------------
// Kernel C: row softmax over k=1024.  One block (256 thr) per (b,q) row.
// Writes attention weights `a` directly into d_out.
// ---------------------------------------------------------------------------
__global__ __launch_bounds__(256) void aa_softmax_kernel(
    const float* __restrict__ z, float* __restrict__ a)
{
    const int row = blockIdx.x;
    const int t = threadIdx.x;
    const float* zr = z + (size_t)row * 1024;

    float x[4];
    *(float4*)x = *(const float4*)&zr[t * 4];

    float m = fmaxf(fmaxf(x[0], x[1]), fmaxf(x[2], x[3]));
#pragma unroll
    for (int off = 32; off; off >>= 1) m = fmaxf(m, __shfl_xor(m, off));

    __shared__ float redm[4];
    __shared__ float reds[4];
    const int wid = t >> 6;
    if ((t & 63) == 0) redm[wid] = m;
    __syncthreads();
    m = fmaxf(fmaxf(redm[0], redm[1]), fmaxf(redm[2], redm[3]));

    float e[4];
    float s = 0.f;
#pragma unroll
    for (int j = 0; j < 4; ++j) {
        e[j] = __builtin_amdgcn_exp2f((x[j] - m) * L2E);
        s += e[j];
    }
#pragma unroll
    for (int off = 32; off; off >>= 1) s += __shfl_xor(s, off);
    if ((t & 63) == 0) reds[wid] = s;
    __syncthreads();
    s = reds[0] + reds[1] + reds[2] + reds[3];

    const float inv = __builtin_amdgcn_rcpf(s);
    float o[4];
#pragma unroll
    for (int j = 0; j < 4; ++j) o[j] = e[j] * inv;
    *(float4*)&a[(size_t)row * 1024 + t * 4] = *(float4*)o;
}

// ---------------------------------------------------------------------------
// Kernel D1: split-4 PV partial.  Grid 256 = 4b x 16qt x 4kt, 512 thr.
// Block tile: 16q x 256v over a 256-k chunk; wave w takes k-sub [w*32,+32).
// part layout: [bid][16 q][256 v], bid = (b*16+qt)*4+kt.
// ---------------------------------------------------------------------------
__global__ __launch_bounds__(512) void aa_pv_partial_kernel(
    const float* __restrict__ a, const float* __restrict__ value,
    float* __restrict__ part)
{
    __shared__ float a_s[16][256];      // 16 KB
    __shared__ float red_s[8][4096];    // 128 KB
    const int bid = blockIdx.x;
    const int b  = bid >> 6;
    const int qt = (bid >> 2) & 15;
    const int kt = bid & 3;
    const int t = threadIdx.x;

    // stage a[16 rows][kt*256 .. +256) into LDS
#pragma unroll
    for (int j = 0; j < 2; ++j) {
        const int f = t * 4 + j * 2048;
        const int qs = f >> 8;
        const int k0 = f & 255;
        const float* arow = a + (size_t)(b * 256 + qt * 16 + qs) * 1024 + kt * 256;
        *(float4*)&a_s[qs][k0] = *(const float4*)&arow[k0];
    }
    __syncthreads();

    const int w = t >> 6;       // 0..7, k-sub = w*32
    const int lane = t & 63;
    const int v0 = lane * 4;    // 64 lanes x 4 = 256 v
    const float* vp = value + (size_t)b * 262144
                    + (size_t)(kt * 256 + w * 32) * 256 + v0;

    float acc[16][4] = {};

#pragma unroll 2
    for (int k4 = 0; k4 < 8; ++k4) {          // 8 groups of 4 k
        float vv[4][4];
#pragma unroll
        for (int r = 0; r < 4; ++r)
            *(float4*)vv[r] = *(const float4*)(vp + (size_t)(k4 * 4 + r) * 256);
#pragma unroll
        for (int q = 0; q < 16; ++q) {
            float aq[4];
            *(float4*)aq = *(const float4*)&a_s[q][w * 32 + k4 * 4];
#pragma unroll
            for (int r = 0; r < 4; ++r)
#pragma unroll
                for (int c = 0; c < 4; ++c)
                    acc[q][c] = fmaf(aq[r], vv[r][c], acc[q][c]);
        }
    }

    // stage wave partials: red_s[w][q*256 + v]
    float* rs = &red_s[w][v0];
#pragma unroll
    for (int q = 0; q < 16; ++q)
        *(float4*)(rs + q * 256) = *(float4*)acc[q];
    __syncthreads();

    // combine 8 waves; thread t sums float4 at i = c*2048 + t*4 (c=0,1)
    float* po = part + (size_t)bid * 4096;
#pragma unroll
    for (int c = 0; c < 2; ++c) {
        const int i = c * 2048 + t * 4;
        float s[4];
        *(float4*)s = *(const float4*)&red_s[0][i];
#pragma unroll
        for (int ww = 1; ww < 8; ++ww) {
            float x[4];
            *(float4*)x = *(const float4*)&red_s[ww][i];
            s[0] += x[0]; s[1] += x[1]; s[2] += x[2]; s[3] += x[3];
        }
        *(float4*)(po + i) = *(float4*)s;
    }
}

// ---------------------------------------------------------------------------
// Kernel D2: fixed-order 4-way reduce of partials -> out.
// part layout: [(b*16+qt)*4+kt][16 q][256 v].
// ---------------------------------------------------------------------------
__global__ __launch_bounds__(256) void aa_pv_reduce_kernel(
    const float* __restrict__ part, float* __restrict__ out)
{
    const int idx = blockIdx.x * 256 + threadIdx.x;
    const int o = idx * 4;
    const int row = o >> 8;
    const int v = o & 255;
    const int b = row >> 8;
    const int q = row & 255;
    const int qt = q >> 4;
    const int qr = q & 15;
    const float* p = part + (size_t)((b * 16 + qt) * 4) * 4096 + qr * 256 + v;

    float s[4] = {0.f, 0.f, 0.f, 0.f};
#pragma unroll
    for (int kt = 0; kt < 4; ++kt) {
        float x[4];
        *(float4*)x = *(const float4*)(p + (size_t)kt * 4096);
        s[0] += x[0]; s[1] += x[1]; s[2] += x[2]; s[3] += x[3];
    }
    *(float4*)&out[o] = *(float4*)s;
}

// ---------------------------------------------------------------------------
extern "C" void kernel_launch(void* const* d_in, const int* in_sizes, int n_in,
                              void* d_out, int out_size, void* d_ws, size_t ws_size,
                              hipStream_t stream)
{
    const float* query = (const float*)d_in[0];  // (4,256,256)
    const float* key   = (const float*)d_in[1];  // (4,1024,256)
    const float* value = (const float*)d_in[2];  // (4,1024,256)
    const float* wq    = (const float*)d_in[3];  // (256,128)
    const float* wk    = (const float*)d_in[4];  // (256,128)
    const float* wv    = (const float*)d_in[5];  // (128,)

    float* out   = (float*)d_out;                // (4,256,256)
    float* a_out = out + 4 * 256 * 256;          // (4,256,1024)

    float* ws = (float*)d_ws;
    float* Eq   = ws;                                  // 131072 f32
    float* Ek   = ws + 131072;                         // 524288 f32
    float* z    = ws + 131072 + 524288;                // 1048576 f32
    float* part = ws + 131072 + 524288 + 1048576;      // 1048576 f32 (4 MB)

    aa_proj_kernel<<<320, 256, 0, stream>>>(query, key, wq, wk, Eq, Ek);
    aa_score_kernel<<<512, 256, 0, stream>>>(Eq, Ek, wv, z);
    aa_softmax_kernel<<<1024, 256, 0, stream>>>(z, a_out);
    aa_pv_partial_kernel<<<256, 512, 0, stream>>>(a_out, value, part);
    aa_pv_reduce_kernel<<<256, 256, 0, stream>>>(part, out);
}

// Round 4
// 48.687 us; speedup vs baseline: 1.6057x; 1.0098x over previous
//
#include <hip/hip_runtime.h>

// Additive (Bahdanau) attention, f32.
// b=4, q=256, k=1024, emb=256, h=128, v=256.
// out  = (4,256,256)  at d_out offset 0
// attn = (4,256,1024) at d_out offset 262144
//
// tanh(Hq+Hk) = 1 - 2/(e^{2Hq}*e^{2Hk} + 1).  Projections store
// Eq = exp2(2*log2e*Hq), Ek = exp2(2*log2e*Hk).  Scores fold FOUR h-terms
// into ONE rcp:  w0/A+w1/B+w2/C+w3/D = (n01*CD + n23*AB) * rcp(AB*CD).
// Softmax is shift-invariant -> constant Wsum dropped: z' = -2*sum_h w_h/(EqEk+1).
// Split-softmax: B emits per-128k-tile (max, sumexp) stats; D1 reduces the 8
// stats per row, converts z->a during its staging read, writes a, and does PV.
// Kernels: A (proj) | B (scores+stats) | D1 (softmax-finish + PV) | D2 (reduce).

#define L2E 1.4426950408889634f

// ---------------------------------------------------------------------------
// Kernel A: projections + exp epilogue.  Eq = exp2(2L2E*(query@wq)), same Ek.
// Blocks 0..63 -> Eq (1024 rows), 64..319 -> Ek (4096 rows).
// W staged through LDS in 64-row e-chunks (32 KB): each block reads the
// 128 KB weight matrix from global exactly once.
// ---------------------------------------------------------------------------
__global__ __launch_bounds__(256) void aa_proj_kernel(
    const float* __restrict__ query, const float* __restrict__ key,
    const float* __restrict__ wq, const float* __restrict__ wk,
    float* __restrict__ Eq, float* __restrict__ Ek)
{
    __shared__ float rows_s[16 * 256];   // 16 KB
    __shared__ float w_s[64 * 128];      // 32 KB
    const int i = blockIdx.x;
    const int t = threadIdx.x;

    const float* src;
    const float* W;
    float* dst;
    if (i < 64) {
        const int r0 = i * 16;
        src = query + r0 * 256; W = wq; dst = Eq + r0 * 128;
    } else {
        const int r0 = (i - 64) * 16;
        src = key + r0 * 256; W = wk; dst = Ek + r0 * 128;
    }

#pragma unroll
    for (int j = 0; j < 4; ++j) {
        const int f = t * 4 + j * 1024;
        *(float4*)&rows_s[f] = *(const float4*)&src[f];
    }

    const int rgr = t >> 5;
    const int hg = t & 31;
    const int ri0 = rgr * 2;
    const int h0 = hg * 4;

    float acc0[4] = {0.f, 0.f, 0.f, 0.f};
    float acc1[4] = {0.f, 0.f, 0.f, 0.f};

    for (int ec = 0; ec < 256; ec += 64) {
        __syncthreads();   // first iter: covers rows_s; later: w_s readers done
#pragma unroll
        for (int j = 0; j < 8; ++j) {
            const int f = t * 4 + j * 1024;
            *(float4*)&w_s[f] = *(const float4*)&W[ec * 128 + f];
        }
        __syncthreads();

        for (int e = 0; e < 64; e += 4) {
            float a0[4], a1[4];
            *(float4*)a0 = *(const float4*)&rows_s[ri0 * 256 + ec + e];
            *(float4*)a1 = *(const float4*)&rows_s[(ri0 + 1) * 256 + ec + e];
#pragma unroll
            for (int j = 0; j < 4; ++j) {
                float w[4];
                *(float4*)w = *(const float4*)&w_s[(e + j) * 128 + h0];
#pragma unroll
                for (int c = 0; c < 4; ++c) {
                    acc0[c] = fmaf(a0[j], w[c], acc0[c]);
                    acc1[c] = fmaf(a1[j], w[c], acc1[c]);
                }
            }
        }
    }

    float o0[4], o1[4];
#pragma unroll
    for (int c = 0; c < 4; ++c) {
        o0[c] = __builtin_amdgcn_exp2f(acc0[c] * (2.0f * L2E));
        o1[c] = __builtin_amdgcn_exp2f(acc1[c] * (2.0f * L2E));
    }
    *(float4*)&dst[ri0 * 128 + h0] = *(float4*)o0;
    *(float4*)&dst[(ri0 + 1) * 128 + h0] = *(float4*)o1;
}

// ---------------------------------------------------------------------------
// Kernel B: scores z' = -2*sum_h w[h]*rcp(fma(Eq,Ek,1)) + per-tile stats.
// Grid 512 = 4b x 16qt x 8kt; block tile 16q x 128k, 256 thr.
// Thread = 4q x 2k: qp = t>>6 (WAVE-UNIFORM -> eq + wv LDS reads broadcast);
// kp = t&63 -> k cols {kp, kp+64}.  After scores, each wave owns 4 complete
// row-tiles (64 lanes x 2 cols = 128 k) -> shfl-reduce (m, sumexp) per row,
// lane 0 stores stats[bid*16 + row] = {m, s}.
// ---------------------------------------------------------------------------
__global__ __launch_bounds__(256) void aa_score_kernel(
    const float* __restrict__ Eq, const float* __restrict__ Ek,
    const float* __restrict__ wv, float* __restrict__ z,
    float* __restrict__ stats)
{
    __shared__ float eq_s[16 * 128];     // 8 KB
    __shared__ float ek_s[128 * 132];    // 67.6 KB
    __shared__ float wv_s[128];

    const int bid = blockIdx.x;
    const int b  = bid >> 7;
    const int qt = (bid >> 3) & 15;
    const int kt = bid & 7;
    const int q0g = b * 256 + qt * 16;
    const int k0g = b * 1024 + kt * 128;
    const int t = threadIdx.x;

    const float* eqsrc = Eq + (size_t)q0g * 128;
#pragma unroll
    for (int j = 0; j < 2; ++j) {
        const int f = t * 4 + j * 1024;
        *(float4*)&eq_s[f] = *(const float4*)&eqsrc[f];
    }
    const float* eksrc = Ek + (size_t)k0g * 128;
#pragma unroll
    for (int j = 0; j < 16; ++j) {
        const int f = t * 4 + j * 1024;
        const int ki = f >> 7;
        const int h = f & 127;
        *(float4*)&ek_s[ki * 132 + h] = *(const float4*)&eksrc[f];
    }
    if (t < 128) wv_s[t] = wv[t];
    __syncthreads();

    const int qp = t >> 6;     // 0..3, wave-uniform: rows qp*4 .. qp*4+3
    const int kp = t & 63;     // k cols kp, kp+64
    const float* eq0 = eq_s + (qp * 4) * 128;
    const float* eka = ek_s + kp * 132;
    const float* ekb = eka + 64 * 132;

    float acc[4][2] = {};

    // quad-rcp: sum_{j=0..3} w[j]/(x[j]*y[j]+1) with a single rcp.
    auto quad = [](const float* x, const float* y, const float* w, float& acc) {
        const float A = fmaf(x[0], y[0], 1.0f);
        const float B = fmaf(x[1], y[1], 1.0f);
        const float C = fmaf(x[2], y[2], 1.0f);
        const float D = fmaf(x[3], y[3], 1.0f);
        const float AB = A * B;
        const float CD = C * D;
        const float n01 = fmaf(w[1], A, w[0] * B);
        const float n23 = fmaf(w[3], C, w[2] * D);
        const float num = fmaf(n01, CD, n23 * AB);
        acc = fmaf(num, __builtin_amdgcn_rcpf(AB * CD), acc);
    };

#pragma unroll 4
    for (int h = 0; h < 128; h += 4) {
        float y0[4], y1[4], w4[4];
        *(float4*)y0 = *(const float4*)(eka + h);
        *(float4*)y1 = *(const float4*)(ekb + h);
        *(float4*)w4 = *(const float4*)(wv_s + h);
#pragma unroll
        for (int i = 0; i < 4; ++i) {
            float x[4];
            *(float4*)x = *(const float4*)(eq0 + i * 128 + h);   // broadcast
            quad(x, y0, w4, acc[i][0]);
            quad(x, y1, w4, acc[i][1]);
        }
    }

    const int kl = kt * 128 + kp;
#pragma unroll
    for (int i = 0; i < 4; ++i) {
        const float z0 = -2.0f * acc[i][0];
        const float z1 = -2.0f * acc[i][1];
        float* zr = z + (size_t)(q0g + qp * 4 + i) * 1024 + kl;
        zr[0]  = z0;
        zr[64] = z1;

        // per-row tile stats: max + sum(exp) over this 128-k tile
        float mx = fmaxf(z0, z1);
#pragma unroll
        for (int off = 32; off; off >>= 1) mx = fmaxf(mx, __shfl_xor(mx, off));
        float e = __builtin_amdgcn_exp2f((z0 - mx) * L2E)
                + __builtin_amdgcn_exp2f((z1 - mx) * L2E);
#pragma unroll
        for (int off = 32; off; off >>= 1) e += __shfl_xor(e, off);
        if (kp == 0) {
            float* sp = stats + (size_t)(bid * 16 + qp * 4 + i) * 2;
            sp[0] = mx;
            sp[1] = e;
        }
    }
}

// ---------------------------------------------------------------------------
// Kernel D1: softmax-finish + split-4 PV partial.
// Grid 256 = 4b x 16qt x 4kt, 512 thr.
// Phase 0: reduce 8 tile-stats per row -> (m, 1/s) in LDS.
// Phase 1: stage z tile 16q x 256k, convert e = exp2((z-m)L2E)/s on the fly,
//          write attention weights a (d_out) + LDS a_s.
// Phase 2: PV: block tile 16q x 256v over 256-k chunk; wave w = k-sub 32.
// part layout: [bid][16 q][256 v], bid = (b*16+qt)*4+kt.
// ---------------------------------------------------------------------------
__global__ __launch_bounds__(512) void aa_pv_partial_kernel(
    const float* __restrict__ z, const float* __restrict__ stats,
    const float* __restrict__ value,
    float* __restrict__ a, float* __restrict__ part)
{
    __shared__ float a_s[16][256];      // 16 KB
    __shared__ float red_s[8][4096];    // 128 KB
    __shared__ float ms_s[16];
    __shared__ float is_s[16];
    const int bid = blockIdx.x;
    const int b  = bid >> 6;
    const int qt = (bid >> 2) & 15;
    const int kt = bid & 3;
    const int t = threadIdx.x;

    // phase 0: per-row global (m, 1/s) from the 8 B-tiles of this (b,qt)
    if (t < 16) {
        const float* st = stats + (size_t)(b * 128 + qt * 8) * 32;  // 8 kt x 16 rows x 2
        float mloc[8], sloc[8];
#pragma unroll
        for (int k8 = 0; k8 < 8; ++k8) {
            mloc[k8] = st[(k8 * 16 + t) * 2];
            sloc[k8] = st[(k8 * 16 + t) * 2 + 1];
        }
        float m = mloc[0];
#pragma unroll
        for (int k8 = 1; k8 < 8; ++k8) m = fmaxf(m, mloc[k8]);
        float s = 0.f;
#pragma unroll
        for (int k8 = 0; k8 < 8; ++k8)
            s = fmaf(sloc[k8], __builtin_amdgcn_exp2f((mloc[k8] - m) * L2E), s);
        ms_s[t] = m;
        is_s[t] = __builtin_amdgcn_rcpf(s);
    }
    __syncthreads();

    // phase 1: stage z -> a (LDS + global d_out)
#pragma unroll
    for (int j = 0; j < 2; ++j) {
        const int f = t * 4 + j * 2048;
        const int qs = f >> 8;          // wave-uniform
        const int k0 = f & 255;
        const size_t roff = (size_t)(b * 256 + qt * 16 + qs) * 1024 + kt * 256 + k0;
        float x[4], o[4];
        *(float4*)x = *(const float4*)&z[roff];
        const float m = ms_s[qs];
        const float inv = is_s[qs];
#pragma unroll
        for (int c = 0; c < 4; ++c)
            o[c] = __builtin_amdgcn_exp2f((x[c] - m) * L2E) * inv;
        *(float4*)&a_s[qs][k0] = *(float4*)o;
        *(float4*)&a[roff] = *(float4*)o;
    }
    __syncthreads();

    // phase 2: PV
    const int w = t >> 6;       // 0..7, k-sub = w*32
    const int lane = t & 63;
    const int v0 = lane * 4;    // 64 lanes x 4 = 256 v
    const float* vp = value + (size_t)b * 262144
                    + (size_t)(kt * 256 + w * 32) * 256 + v0;

    float acc[16][4] = {};

#pragma unroll 2
    for (int k4 = 0; k4 < 8; ++k4) {          // 8 groups of 4 k
        float vv[4][4];
#pragma unroll
        for (int r = 0; r < 4; ++r)
            *(float4*)vv[r] = *(const float4*)(vp + (size_t)(k4 * 4 + r) * 256);
#pragma unroll
        for (int q = 0; q < 16; ++q) {
            float aq[4];
            *(float4*)aq = *(const float4*)&a_s[q][w * 32 + k4 * 4];
#pragma unroll
            for (int r = 0; r < 4; ++r)
#pragma unroll
                for (int c = 0; c < 4; ++c)
                    acc[q][c] = fmaf(aq[r], vv[r][c], acc[q][c]);
        }
    }

    // stage wave partials: red_s[w][q*256 + v]
    float* rs = &red_s[w][v0];
#pragma unroll
    for (int q = 0; q < 16; ++q)
        *(float4*)(rs + q * 256) = *(float4*)acc[q];
    __syncthreads();

    // combine 8 waves; thread t sums float4 at i = c*2048 + t*4 (c=0,1)
    float* po = part + (size_t)bid * 4096;
#pragma unroll
    for (int c = 0; c < 2; ++c) {
        const int i = c * 2048 + t * 4;
        float s[4];
        *(float4*)s = *(const float4*)&red_s[0][i];
#pragma unroll
        for (int ww = 1; ww < 8; ++ww) {
            float x[4];
            *(float4*)x = *(const float4*)&red_s[ww][i];
            s[0] += x[0]; s[1] += x[1]; s[2] += x[2]; s[3] += x[3];
        }
        *(float4*)(po + i) = *(float4*)s;
    }
}

// ---------------------------------------------------------------------------
// Kernel D2: fixed-order 4-way reduce of partials -> out.
// part layout: [(b*16+qt)*4+kt][16 q][256 v].
// ---------------------------------------------------------------------------
__global__ __launch_bounds__(256) void aa_pv_reduce_kernel(
    const float* __restrict__ part, float* __restrict__ out)
{
    const int idx = blockIdx.x * 256 + threadIdx.x;
    const int o = idx * 4;
    const int row = o >> 8;
    const int v = o & 255;
    const int b = row >> 8;
    const int q = row & 255;
    const int qt = q >> 4;
    const int qr = q & 15;
    const float* p = part + (size_t)((b * 16 + qt) * 4) * 4096 + qr * 256 + v;

    float s[4] = {0.f, 0.f, 0.f, 0.f};
#pragma unroll
    for (int kt = 0; kt < 4; ++kt) {
        float x[4];
        *(float4*)x = *(const float4*)(p + (size_t)kt * 4096);
        s[0] += x[0]; s[1] += x[1]; s[2] += x[2]; s[3] += x[3];
    }
    *(float4*)&out[o] = *(float4*)s;
}

// ---------------------------------------------------------------------------
extern "C" void kernel_launch(void* const* d_in, const int* in_sizes, int n_in,
                              void* d_out, int out_size, void* d_ws, size_t ws_size,
                              hipStream_t stream)
{
    const float* query = (const float*)d_in[0];  // (4,256,256)
    const float* key   = (const float*)d_in[1];  // (4,1024,256)
    const float* value = (const float*)d_in[2];  // (4,1024,256)
    const float* wq    = (const float*)d_in[3];  // (256,128)
    const float* wk    = (const float*)d_in[4];  // (256,128)
    const float* wv    = (const float*)d_in[5];  // (128,)

    float* out   = (float*)d_out;                // (4,256,256)
    float* a_out = out + 4 * 256 * 256;          // (4,256,1024)

    float* ws = (float*)d_ws;
    float* Eq    = ws;                                  // 131072 f32
    float* Ek    = ws + 131072;                         // 524288 f32
    float* z     = ws + 131072 + 524288;                // 1048576 f32
    float* part  = ws + 131072 + 524288 + 1048576;      // 1048576 f32
    float* stats = ws + 131072 + 524288 + 2097152;      // 16384 f32

    aa_proj_kernel<<<320, 256, 0, stream>>>(query, key, wq, wk, Eq, Ek);
    aa_score_kernel<<<512, 256, 0, stream>>>(Eq, Ek, wv, z, stats);
    aa_pv_partial_kernel<<<256, 512, 0, stream>>>(z, stats, value, a_out, part);
    aa_pv_reduce_kernel<<<256, 256, 0, stream>>>(part, out);
}